// Round 9
// baseline (496.194 us; speedup 1.0000x reference)
//
#include <hip/hip_runtime.h>

// UnstructuredNetwork via fp16 MFMA (v_mfma_f32_32x32x16_f16), fp32 accumulate.
// R9: exact R7 structure (inline-asm R8 tripped the harness determinism
// tripwire -- reverted; lesson: no bare asm in the MFMA dep chain).
// Single change: __launch_bounds__(256,2). R7's VGPR_Count=40 proves all four
// floatx16 accumulators live in AGPRs => ~48 v_accvgpr_read/layer marshalling
// (the missing ~100 cyc/wave-layer in the issue accounting). A 256-reg budget
// lets the allocator keep C/D in arch VGPRs (gfx950 unified file).
// Structure: phi-permuted weights => C pairs == B fragments verbatim
// (no shfl/cndmask); 64 samples/wave (2 B-groups share A frags);
// h residual packed f16 (RNE fma); t-feed RTZ pkrtz (within-layer only);
// double-buffered weight prefetch.

#define HID 20
#define NLAYERS 50
#define NEG 0.01f

typedef _Float16 half8   __attribute__((ext_vector_type(8)));
typedef _Float16 half2v  __attribute__((ext_vector_type(2)));
typedef __fp16   fp16x2  __attribute__((ext_vector_type(2)));
typedef float    floatx16 __attribute__((ext_vector_type(16)));
typedef unsigned uint4v  __attribute__((ext_vector_type(4)));

__device__ __forceinline__ unsigned pack_rne(float a, float b) {
    half2v p;
    p[0] = (_Float16)a;   // v_cvt_f16_f32 (RNE)
    p[1] = (_Float16)b;
    return __builtin_bit_cast(unsigned, p);
}

// position->k involution: swap 4-7 <-> 8-11, fix the rest
__device__ __forceinline__ int phi(int k) {
    if (k >= 4 && k < 8)  return k + 4;
    if (k >= 8 && k < 12) return k - 4;
    return k;
}

// ---------------- prepass: build A-operand fragments -----------------------
// A'[m][k] = W[phi(k)][m] (k<20), A'[m][20] = b[m], 0 otherwise.
// Lane l holds m=l&31, k = 16*ks + 8*(l>>5) + j (j=0..7).
// ws layout: wf[((L*2 + mk)*2 + ks)*64 + lane] : half8 ; then 50 packed dt f16x2.
__global__ void build_wfrags(const float* __restrict__ W1, const float* __restrict__ b1,
                             const float* __restrict__ W2, const float* __restrict__ b2,
                             const float* __restrict__ dts,
                             half8* __restrict__ wf)
{
    const int L = blockIdx.x;
    const int l = threadIdx.x;           // 0..63
    const int m = l & 31, hh = l >> 5;
    const float* Ws[2] = { W1 + L * HID * HID, W2 + L * HID * HID };
    const float* bs[2] = { b1 + L * HID,       b2 + L * HID };
#pragma unroll
    for (int mk = 0; mk < 2; ++mk) {
#pragma unroll
        for (int ks = 0; ks < 2; ++ks) {
            half8 frag;
#pragma unroll
            for (int j = 0; j < 8; ++j) {
                int k = ks * 16 + hh * 8 + j;
                float v = 0.0f;
                if (m < HID) {
                    if (k < HID) v = Ws[mk][phi(k) * HID + m];
                    else if (k == HID) v = bs[mk][m];
                }
                frag[j] = (_Float16)v;
            }
            wf[((L * 2 + mk) * 2 + ks) * 64 + l] = frag;
        }
    }
    if (l == 0) {
        unsigned* dtp = (unsigned*)(wf + NLAYERS * 256);
        const __fp16 d = (__fp16)dts[L];
        fp16x2 dp = {d, d};
        dtp[L] = __builtin_bit_cast(unsigned, dp);
    }
}

// ---------------- main kernel --------------------------------------------
__global__ __launch_bounds__(256, 2) void unet_mfma(
    const float* __restrict__ x,
    const float* __restrict__ lift_w,
    const float* __restrict__ lift_b,
    const float* __restrict__ proj_w,
    const float* __restrict__ proj_b,
    const half8* __restrict__ wf,
    float* __restrict__ out, int Bn)
{
    const int tid = threadIdx.x;
    const int wv  = tid >> 6;
    const int l   = tid & 63;
    const int n   = l & 31;
    const int hh  = l >> 5;

    const int gA  = blockIdx.x * 256 + wv * 64 + n;   // group A sample
    const int gB  = gA + 32;                          // group B sample
    const int giA = gA < Bn ? gA : Bn - 1;
    const int giB = gB < Bn ? gB : Bn - 1;

    const unsigned C10 = 0x00003C00u;   // f16 (1.0, 0.0): k20 bias, k21 = 0
    const fp16x2  negs = {(__fp16)NEG, (__fp16)NEG};

    // ---- lift both groups (fp32 -> RNE f16 pairs, C-layout rows) ----
    fp16x2 hA[6], hB[6];
    unsigned hpA[6], hpB[6];
    {
        const float xA0 = x[3 * giA + 0], xA1 = x[3 * giA + 1], xA2 = x[3 * giA + 2];
        const float xB0 = x[3 * giB + 0], xB1 = x[3 * giB + 1], xB2 = x[3 * giB + 2];
#pragma unroll
        for (int i = 0; i < 6; ++i) {
            const int r0   = 2 * i;
            const int row0 = (r0 & 3) + 8 * (r0 >> 2) + 4 * hh;
            float vA[2], vB[2];
#pragma unroll
            for (int e = 0; e < 2; ++e) {
                const int row = row0 + e;
                if (row < HID) {
                    const float w0 = lift_w[0 * HID + row];
                    const float w1 = lift_w[1 * HID + row];
                    const float w2 = lift_w[2 * HID + row];
                    const float b  = lift_b[row];
                    vA[e] = fmaf(xA2, w2, fmaf(xA1, w1, fmaf(xA0, w0, b)));
                    vB[e] = fmaf(xB2, w2, fmaf(xB1, w1, fmaf(xB0, w0, b)));
                } else { vA[e] = 0.0f; vB[e] = 0.0f; }
            }
            hpA[i] = pack_rne(vA[0], vA[1]);
            hpB[i] = pack_rne(vB[0], vB[1]);
        }
    }
#pragma unroll
    for (int i = 0; i < 6; ++i) {
        hA[i] = __builtin_bit_cast(fp16x2, hpA[i]);
        hB[i] = __builtin_bit_cast(fp16x2, hpB[i]);
    }

    floatx16 zf;
#pragma unroll
    for (int i = 0; i < 16; ++i) zf[i] = 0.0f;

    const unsigned* __restrict__ dtp = (const unsigned*)(wf + NLAYERS * 256);

    half8 bhA0 = __builtin_bit_cast(half8, (uint4v){hpA[0], hpA[1], hpA[2], hpA[3]});
    half8 bhA1 = __builtin_bit_cast(half8, (uint4v){hpA[4], hpA[5], C10, 0u});
    half8 bhB0 = __builtin_bit_cast(half8, (uint4v){hpB[0], hpB[1], hpB[2], hpB[3]});
    half8 bhB1 = __builtin_bit_cast(half8, (uint4v){hpB[4], hpB[5], C10, 0u});

    // ---- double-buffered weight prefetch ----
    const half8* __restrict__ wl = wf + l;
    half8 c0 = wl[0], c1 = wl[64], c2 = wl[128], c3 = wl[192];

    for (int L = 0; L < NLAYERS; ++L) {
        // prefetch layer L+1 (last iter refetches layer 49; in-bounds, unused)
        const int Ln = (L + 1 < NLAYERS) ? (L + 1) : (NLAYERS - 1);
        const half8* __restrict__ wn = wf + l + Ln * 256;
        const half8 p0 = wn[0], p1 = wn[64], p2 = wn[128], p3 = wn[192];

        const fp16x2 dt2 = __builtin_bit_cast(fp16x2, dtp[L]);

        // matmul1 both groups (independent MFMA stream)
        floatx16 accA = __builtin_amdgcn_mfma_f32_32x32x16_f16(c0, bhA0, zf, 0, 0, 0);
        floatx16 accB = __builtin_amdgcn_mfma_f32_32x32x16_f16(c0, bhB0, zf, 0, 0, 0);
        accA = __builtin_amdgcn_mfma_f32_32x32x16_f16(c1, bhA1, accA, 0, 0, 0);
        accB = __builtin_amdgcn_mfma_f32_32x32x16_f16(c1, bhB1, accB, 0, 0, 0);

        // t-feed: pkrtz + packed-f16 leaky; pairs ARE the next B fragments
        unsigned tpA[6], tpB[6];
#pragma unroll
        for (int i = 0; i < 6; ++i) {
            fp16x2 zA = __builtin_amdgcn_cvt_pkrtz(accA[2 * i], accA[2 * i + 1]);
            fp16x2 zB = __builtin_amdgcn_cvt_pkrtz(accB[2 * i], accB[2 * i + 1]);
            fp16x2 tA = __builtin_elementwise_max(zA, zA * negs);
            fp16x2 tB = __builtin_elementwise_max(zB, zB * negs);
            tpA[i] = __builtin_bit_cast(unsigned, tA);
            tpB[i] = __builtin_bit_cast(unsigned, tB);
        }
        const half8 btA0 = __builtin_bit_cast(half8, (uint4v){tpA[0], tpA[1], tpA[2], tpA[3]});
        const half8 btA1 = __builtin_bit_cast(half8, (uint4v){tpA[4], tpA[5], C10, 0u});
        const half8 btB0 = __builtin_bit_cast(half8, (uint4v){tpB[0], tpB[1], tpB[2], tpB[3]});
        const half8 btB1 = __builtin_bit_cast(half8, (uint4v){tpB[4], tpB[5], C10, 0u});

        // matmul2 both groups
        floatx16 acc2A = __builtin_amdgcn_mfma_f32_32x32x16_f16(c2, btA0, zf, 0, 0, 0);
        floatx16 acc2B = __builtin_amdgcn_mfma_f32_32x32x16_f16(c2, btB0, zf, 0, 0, 0);
        acc2A = __builtin_amdgcn_mfma_f32_32x32x16_f16(c3, btA1, acc2A, 0, 0, 0);
        acc2B = __builtin_amdgcn_mfma_f32_32x32x16_f16(c3, btB1, acc2B, 0, 0, 0);

        // residual in packed f16 (RNE fma): h += dt * max(u, 0.01u)
#pragma unroll
        for (int i = 0; i < 6; ++i) {
            fp16x2 zA = __builtin_amdgcn_cvt_pkrtz(acc2A[2 * i], acc2A[2 * i + 1]);
            fp16x2 zB = __builtin_amdgcn_cvt_pkrtz(acc2B[2 * i], acc2B[2 * i + 1]);
            fp16x2 lA = __builtin_elementwise_max(zA, zA * negs);
            fp16x2 lB = __builtin_elementwise_max(zB, zB * negs);
            hA[i] = __builtin_elementwise_fma(dt2, lA, hA[i]);
            hB[i] = __builtin_elementwise_fma(dt2, lB, hB[i]);
            hpA[i] = __builtin_bit_cast(unsigned, hA[i]);
            hpB[i] = __builtin_bit_cast(unsigned, hB[i]);
        }
        bhA0 = __builtin_bit_cast(half8, (uint4v){hpA[0], hpA[1], hpA[2], hpA[3]});
        bhA1 = __builtin_bit_cast(half8, (uint4v){hpA[4], hpA[5], C10, 0u});
        bhB0 = __builtin_bit_cast(half8, (uint4v){hpB[0], hpB[1], hpB[2], hpB[3]});
        bhB1 = __builtin_bit_cast(half8, (uint4v){hpB[4], hpB[5], C10, 0u});

        // rotate weight buffers
        c0 = p0; c1 = p1; c2 = p2; c3 = p3;
    }

    // ---- projection, both groups ----
    float aO0 = 0.f, aO1 = 0.f, aO2 = 0.f, bO0 = 0.f, bO1 = 0.f, bO2 = 0.f;
#pragma unroll
    for (int i = 0; i < 6; ++i) {
#pragma unroll
        for (int e = 0; e < 2; ++e) {
            const int r0  = 2 * i;
            const int row = (r0 & 3) + 8 * (r0 >> 2) + 4 * hh + e;
            if (row < HID) {
                const float w0 = proj_w[row * 3 + 0];
                const float w1 = proj_w[row * 3 + 1];
                const float w2 = proj_w[row * 3 + 2];
                const float va = (float)hA[i][e];
                const float vb = (float)hB[i][e];
                aO0 = fmaf(va, w0, aO0); aO1 = fmaf(va, w1, aO1); aO2 = fmaf(va, w2, aO2);
                bO0 = fmaf(vb, w0, bO0); bO1 = fmaf(vb, w1, bO1); bO2 = fmaf(vb, w2, bO2);
            }
        }
    }
    aO0 += __shfl_xor(aO0, 32, 64);
    aO1 += __shfl_xor(aO1, 32, 64);
    aO2 += __shfl_xor(aO2, 32, 64);
    bO0 += __shfl_xor(bO0, 32, 64);
    bO1 += __shfl_xor(bO1, 32, 64);
    bO2 += __shfl_xor(bO2, 32, 64);
    if (hh == 0) {
        if (gA < Bn) {
            out[3 * gA + 0] = aO0 + proj_b[0];
            out[3 * gA + 1] = aO1 + proj_b[1];
            out[3 * gA + 2] = aO2 + proj_b[2];
        }
        if (gB < Bn) {
            out[3 * gB + 0] = bO0 + proj_b[0];
            out[3 * gB + 1] = bO1 + proj_b[1];
            out[3 * gB + 2] = bO2 + proj_b[2];
        }
    }
}

extern "C" void kernel_launch(void* const* d_in, const int* in_sizes, int n_in,
                              void* d_out, int out_size, void* d_ws, size_t ws_size,
                              hipStream_t stream) {
    const float* x      = (const float*)d_in[0];
    const float* lift_w = (const float*)d_in[1];
    const float* lift_b = (const float*)d_in[2];
    const float* W1     = (const float*)d_in[3];
    const float* b1     = (const float*)d_in[4];
    const float* W2     = (const float*)d_in[5];
    const float* b2     = (const float*)d_in[6];
    const float* dts    = (const float*)d_in[7];
    const float* proj_w = (const float*)d_in[8];
    const float* proj_b = (const float*)d_in[9];
    float* out = (float*)d_out;

    const int B = in_sizes[0] / 3;
    half8* wf = (half8*)d_ws;   // NLAYERS*4*64*16 B = 200 KiB + 200 B dt table

    build_wfrags<<<NLAYERS, 64, 0, stream>>>(W1, b1, W2, b2, dts, wf);

    const int blocks = (B + 255) / 256;   // 256 samples/block (4 waves x 64)
    unet_mfma<<<blocks, 256, 0, stream>>>(
        x, lift_w, lift_b, proj_w, proj_b, wf, out, B);
}

// Round 10
// 475.941 us; speedup vs baseline: 1.0426x; 1.0426x over previous
//
#include <hip/hip_runtime.h>

// UnstructuredNetwork via fp16 MFMA (v_mfma_f32_32x32x16_f16), fp32 accumulate.
// R10 = R9 + (a) non-temporal x/out (nt bypasses L2 so the 200 KiB weight set
// stays L2-resident — R9's FETCH_SIZE=12.5 GB showed every per-layer weight
// load missing L2 because the 48 MB x/out stream thrashes the 4 MiB/XCD L2);
// (b) #pragma unroll 2 so the weight double-buffer register-renames (R8
// post-mortem: the tripwire was the inline asm defeating the MFMA hazard
// recognizer — nondeterministic reads; unroll-2 itself is pure dataflow).
// Structure: phi-permuted weights => C pairs == B fragments verbatim
// (no shfl/cndmask); 64 samples/wave (2 B-groups share A frags);
// h residual packed f16 (RNE fma); t-feed RTZ pkrtz (within-layer only);
// one-layer-ahead weight prefetch. NO inline asm in the MFMA dep chain.

#define HID 20
#define NLAYERS 50
#define NEG 0.01f

typedef _Float16 half8   __attribute__((ext_vector_type(8)));
typedef _Float16 half2v  __attribute__((ext_vector_type(2)));
typedef __fp16   fp16x2  __attribute__((ext_vector_type(2)));
typedef float    floatx16 __attribute__((ext_vector_type(16)));
typedef unsigned uint4v  __attribute__((ext_vector_type(4)));

__device__ __forceinline__ unsigned pack_rne(float a, float b) {
    half2v p;
    p[0] = (_Float16)a;   // v_cvt_f16_f32 (RNE)
    p[1] = (_Float16)b;
    return __builtin_bit_cast(unsigned, p);
}

// position->k involution: swap 4-7 <-> 8-11, fix the rest
__device__ __forceinline__ int phi(int k) {
    if (k >= 4 && k < 8)  return k + 4;
    if (k >= 8 && k < 12) return k - 4;
    return k;
}

// ---------------- prepass: build A-operand fragments -----------------------
// A'[m][k] = W[phi(k)][m] (k<20), A'[m][20] = b[m], 0 otherwise.
// Lane l holds m=l&31, k = 16*ks + 8*(l>>5) + j (j=0..7).
// ws layout: wf[((L*2 + mk)*2 + ks)*64 + lane] : half8 ; then 50 packed dt f16x2.
__global__ void build_wfrags(const float* __restrict__ W1, const float* __restrict__ b1,
                             const float* __restrict__ W2, const float* __restrict__ b2,
                             const float* __restrict__ dts,
                             half8* __restrict__ wf)
{
    const int L = blockIdx.x;
    const int l = threadIdx.x;           // 0..63
    const int m = l & 31, hh = l >> 5;
    const float* Ws[2] = { W1 + L * HID * HID, W2 + L * HID * HID };
    const float* bs[2] = { b1 + L * HID,       b2 + L * HID };
#pragma unroll
    for (int mk = 0; mk < 2; ++mk) {
#pragma unroll
        for (int ks = 0; ks < 2; ++ks) {
            half8 frag;
#pragma unroll
            for (int j = 0; j < 8; ++j) {
                int k = ks * 16 + hh * 8 + j;
                float v = 0.0f;
                if (m < HID) {
                    if (k < HID) v = Ws[mk][phi(k) * HID + m];
                    else if (k == HID) v = bs[mk][m];
                }
                frag[j] = (_Float16)v;
            }
            wf[((L * 2 + mk) * 2 + ks) * 64 + l] = frag;
        }
    }
    if (l == 0) {
        unsigned* dtp = (unsigned*)(wf + NLAYERS * 256);
        const __fp16 d = (__fp16)dts[L];
        fp16x2 dp = {d, d};
        dtp[L] = __builtin_bit_cast(unsigned, dp);
    }
}

// ---------------- main kernel --------------------------------------------
__global__ __launch_bounds__(256, 2) void unet_mfma(
    const float* __restrict__ x,
    const float* __restrict__ lift_w,
    const float* __restrict__ lift_b,
    const float* __restrict__ proj_w,
    const float* __restrict__ proj_b,
    const half8* __restrict__ wf,
    float* __restrict__ out, int Bn)
{
    const int tid = threadIdx.x;
    const int wv  = tid >> 6;
    const int l   = tid & 63;
    const int n   = l & 31;
    const int hh  = l >> 5;

    const int gA  = blockIdx.x * 256 + wv * 64 + n;   // group A sample
    const int gB  = gA + 32;                          // group B sample
    const int giA = gA < Bn ? gA : Bn - 1;
    const int giB = gB < Bn ? gB : Bn - 1;

    const unsigned C10 = 0x00003C00u;   // f16 (1.0, 0.0): k20 bias, k21 = 0
    const fp16x2  negs = {(__fp16)NEG, (__fp16)NEG};

    // ---- lift both groups (fp32 -> RNE f16 pairs, C-layout rows) ----
    // x loads non-temporal: keep the 24 MB stream out of L2 (weights live there)
    fp16x2 hA[6], hB[6];
    unsigned hpA[6], hpB[6];
    {
        const float xA0 = __builtin_nontemporal_load(&x[3 * giA + 0]);
        const float xA1 = __builtin_nontemporal_load(&x[3 * giA + 1]);
        const float xA2 = __builtin_nontemporal_load(&x[3 * giA + 2]);
        const float xB0 = __builtin_nontemporal_load(&x[3 * giB + 0]);
        const float xB1 = __builtin_nontemporal_load(&x[3 * giB + 1]);
        const float xB2 = __builtin_nontemporal_load(&x[3 * giB + 2]);
#pragma unroll
        for (int i = 0; i < 6; ++i) {
            const int r0   = 2 * i;
            const int row0 = (r0 & 3) + 8 * (r0 >> 2) + 4 * hh;
            float vA[2], vB[2];
#pragma unroll
            for (int e = 0; e < 2; ++e) {
                const int row = row0 + e;
                if (row < HID) {
                    const float w0 = lift_w[0 * HID + row];
                    const float w1 = lift_w[1 * HID + row];
                    const float w2 = lift_w[2 * HID + row];
                    const float b  = lift_b[row];
                    vA[e] = fmaf(xA2, w2, fmaf(xA1, w1, fmaf(xA0, w0, b)));
                    vB[e] = fmaf(xB2, w2, fmaf(xB1, w1, fmaf(xB0, w0, b)));
                } else { vA[e] = 0.0f; vB[e] = 0.0f; }
            }
            hpA[i] = pack_rne(vA[0], vA[1]);
            hpB[i] = pack_rne(vB[0], vB[1]);
        }
    }
#pragma unroll
    for (int i = 0; i < 6; ++i) {
        hA[i] = __builtin_bit_cast(fp16x2, hpA[i]);
        hB[i] = __builtin_bit_cast(fp16x2, hpB[i]);
    }

    floatx16 zf;
#pragma unroll
    for (int i = 0; i < 16; ++i) zf[i] = 0.0f;

    const unsigned* __restrict__ dtp = (const unsigned*)(wf + NLAYERS * 256);

    half8 bhA0 = __builtin_bit_cast(half8, (uint4v){hpA[0], hpA[1], hpA[2], hpA[3]});
    half8 bhA1 = __builtin_bit_cast(half8, (uint4v){hpA[4], hpA[5], C10, 0u});
    half8 bhB0 = __builtin_bit_cast(half8, (uint4v){hpB[0], hpB[1], hpB[2], hpB[3]});
    half8 bhB1 = __builtin_bit_cast(half8, (uint4v){hpB[4], hpB[5], C10, 0u});

    // ---- double-buffered weight prefetch; unroll 2 => rotation renames ----
    const half8* __restrict__ wl = wf + l;
    half8 c0 = wl[0], c1 = wl[64], c2 = wl[128], c3 = wl[192];

#pragma unroll 2
    for (int L = 0; L < NLAYERS; ++L) {
        // prefetch layer L+1 (last iter refetches layer 49; in-bounds, unused)
        const int Ln = (L + 1 < NLAYERS) ? (L + 1) : (NLAYERS - 1);
        const half8* __restrict__ wn = wf + l + Ln * 256;
        const half8 p0 = wn[0], p1 = wn[64], p2 = wn[128], p3 = wn[192];

        const fp16x2 dt2 = __builtin_bit_cast(fp16x2, dtp[L]);

        // matmul1 both groups (independent MFMA stream)
        floatx16 accA = __builtin_amdgcn_mfma_f32_32x32x16_f16(c0, bhA0, zf, 0, 0, 0);
        floatx16 accB = __builtin_amdgcn_mfma_f32_32x32x16_f16(c0, bhB0, zf, 0, 0, 0);
        accA = __builtin_amdgcn_mfma_f32_32x32x16_f16(c1, bhA1, accA, 0, 0, 0);
        accB = __builtin_amdgcn_mfma_f32_32x32x16_f16(c1, bhB1, accB, 0, 0, 0);

        // t-feed: pkrtz + packed-f16 leaky; pairs ARE the next B fragments
        unsigned tpA[6], tpB[6];
#pragma unroll
        for (int i = 0; i < 6; ++i) {
            fp16x2 zA = __builtin_amdgcn_cvt_pkrtz(accA[2 * i], accA[2 * i + 1]);
            fp16x2 zB = __builtin_amdgcn_cvt_pkrtz(accB[2 * i], accB[2 * i + 1]);
            fp16x2 tA = __builtin_elementwise_max(zA, zA * negs);
            fp16x2 tB = __builtin_elementwise_max(zB, zB * negs);
            tpA[i] = __builtin_bit_cast(unsigned, tA);
            tpB[i] = __builtin_bit_cast(unsigned, tB);
        }
        const half8 btA0 = __builtin_bit_cast(half8, (uint4v){tpA[0], tpA[1], tpA[2], tpA[3]});
        const half8 btA1 = __builtin_bit_cast(half8, (uint4v){tpA[4], tpA[5], C10, 0u});
        const half8 btB0 = __builtin_bit_cast(half8, (uint4v){tpB[0], tpB[1], tpB[2], tpB[3]});
        const half8 btB1 = __builtin_bit_cast(half8, (uint4v){tpB[4], tpB[5], C10, 0u});

        // matmul2 both groups
        floatx16 acc2A = __builtin_amdgcn_mfma_f32_32x32x16_f16(c2, btA0, zf, 0, 0, 0);
        floatx16 acc2B = __builtin_amdgcn_mfma_f32_32x32x16_f16(c2, btB0, zf, 0, 0, 0);
        acc2A = __builtin_amdgcn_mfma_f32_32x32x16_f16(c3, btA1, acc2A, 0, 0, 0);
        acc2B = __builtin_amdgcn_mfma_f32_32x32x16_f16(c3, btB1, acc2B, 0, 0, 0);

        // residual in packed f16 (RNE fma): h += dt * max(u, 0.01u)
#pragma unroll
        for (int i = 0; i < 6; ++i) {
            fp16x2 zA = __builtin_amdgcn_cvt_pkrtz(acc2A[2 * i], acc2A[2 * i + 1]);
            fp16x2 zB = __builtin_amdgcn_cvt_pkrtz(acc2B[2 * i], acc2B[2 * i + 1]);
            fp16x2 lA = __builtin_elementwise_max(zA, zA * negs);
            fp16x2 lB = __builtin_elementwise_max(zB, zB * negs);
            hA[i] = __builtin_elementwise_fma(dt2, lA, hA[i]);
            hB[i] = __builtin_elementwise_fma(dt2, lB, hB[i]);
            hpA[i] = __builtin_bit_cast(unsigned, hA[i]);
            hpB[i] = __builtin_bit_cast(unsigned, hB[i]);
        }
        bhA0 = __builtin_bit_cast(half8, (uint4v){hpA[0], hpA[1], hpA[2], hpA[3]});
        bhA1 = __builtin_bit_cast(half8, (uint4v){hpA[4], hpA[5], C10, 0u});
        bhB0 = __builtin_bit_cast(half8, (uint4v){hpB[0], hpB[1], hpB[2], hpB[3]});
        bhB1 = __builtin_bit_cast(half8, (uint4v){hpB[4], hpB[5], C10, 0u});

        // rotate weight buffers (register-renamed across the unroll-2 body)
        c0 = p0; c1 = p1; c2 = p2; c3 = p3;
    }

    // ---- projection, both groups ----
    float aO0 = 0.f, aO1 = 0.f, aO2 = 0.f, bO0 = 0.f, bO1 = 0.f, bO2 = 0.f;
#pragma unroll
    for (int i = 0; i < 6; ++i) {
#pragma unroll
        for (int e = 0; e < 2; ++e) {
            const int r0  = 2 * i;
            const int row = (r0 & 3) + 8 * (r0 >> 2) + 4 * hh + e;
            if (row < HID) {
                const float w0 = proj_w[row * 3 + 0];
                const float w1 = proj_w[row * 3 + 1];
                const float w2 = proj_w[row * 3 + 2];
                const float va = (float)hA[i][e];
                const float vb = (float)hB[i][e];
                aO0 = fmaf(va, w0, aO0); aO1 = fmaf(va, w1, aO1); aO2 = fmaf(va, w2, aO2);
                bO0 = fmaf(vb, w0, bO0); bO1 = fmaf(vb, w1, bO1); bO2 = fmaf(vb, w2, bO2);
            }
        }
    }
    aO0 += __shfl_xor(aO0, 32, 64);
    aO1 += __shfl_xor(aO1, 32, 64);
    aO2 += __shfl_xor(aO2, 32, 64);
    bO0 += __shfl_xor(bO0, 32, 64);
    bO1 += __shfl_xor(bO1, 32, 64);
    bO2 += __shfl_xor(bO2, 32, 64);
    if (hh == 0) {
        // out stores non-temporal: 24 MB write stream bypasses L2
        if (gA < Bn) {
            __builtin_nontemporal_store(aO0 + proj_b[0], &out[3 * gA + 0]);
            __builtin_nontemporal_store(aO1 + proj_b[1], &out[3 * gA + 1]);
            __builtin_nontemporal_store(aO2 + proj_b[2], &out[3 * gA + 2]);
        }
        if (gB < Bn) {
            __builtin_nontemporal_store(bO0 + proj_b[0], &out[3 * gB + 0]);
            __builtin_nontemporal_store(bO1 + proj_b[1], &out[3 * gB + 1]);
            __builtin_nontemporal_store(bO2 + proj_b[2], &out[3 * gB + 2]);
        }
    }
}

extern "C" void kernel_launch(void* const* d_in, const int* in_sizes, int n_in,
                              void* d_out, int out_size, void* d_ws, size_t ws_size,
                              hipStream_t stream) {
    const float* x      = (const float*)d_in[0];
    const float* lift_w = (const float*)d_in[1];
    const float* lift_b = (const float*)d_in[2];
    const float* W1     = (const float*)d_in[3];
    const float* b1     = (const float*)d_in[4];
    const float* W2     = (const float*)d_in[5];
    const float* b2     = (const float*)d_in[6];
    const float* dts    = (const float*)d_in[7];
    const float* proj_w = (const float*)d_in[8];
    const float* proj_b = (const float*)d_in[9];
    float* out = (float*)d_out;

    const int B = in_sizes[0] / 3;
    half8* wf = (half8*)d_ws;   // NLAYERS*4*64*16 B = 200 KiB + 200 B dt table

    build_wfrags<<<NLAYERS, 64, 0, stream>>>(W1, b1, W2, b2, dts, wf);

    const int blocks = (B + 255) / 256;   // 256 samples/block (4 waves x 64)
    unet_mfma<<<blocks, 256, 0, stream>>>(
        x, lift_w, lift_b, proj_w, proj_b, wf, out, B);
}